// Round 1
// baseline (281.158 us; speedup 1.0000x reference)
//
#include <hip/hip_runtime.h>

#define NN 8192
#define CC 512

typedef __attribute__((ext_vector_type(8))) short short8;
typedef __attribute__((ext_vector_type(4))) float f32x4;
typedef unsigned short ushort_t;

__device__ __forceinline__ unsigned short f2bf(float f) {
    unsigned int u = __float_as_uint(f);
    u += 0x7FFF + ((u >> 16) & 1);
    return (unsigned short)(u >> 16);
}

__device__ __forceinline__ void gload_lds16(const void* g, void* l) {
    __builtin_amdgcn_global_load_lds((const __attribute__((address_space(1))) unsigned int*)g,
                                     (__attribute__((address_space(3))) unsigned int*)l,
                                     16, 0, 0);
}

// ---------------- Kernel 1: deg = rowsum(adj) + 1;  ds = rsqrt(deg) ----------------
__global__ __launch_bounds__(256) void k_rowsum(const float* __restrict__ adj,
                                                float* __restrict__ ds) {
    int row = blockIdx.x;
    const float4* p = (const float4*)(adj + (size_t)row * NN);
    float s = 0.f;
#pragma unroll
    for (int i = 0; i < 8; ++i) {
        float4 v = p[threadIdx.x + i * 256];
        s += (v.x + v.y) + (v.z + v.w);
    }
#pragma unroll
    for (int off = 32; off > 0; off >>= 1) s += __shfl_down(s, off, 64);
    __shared__ float partial[4];
    int wid = threadIdx.x >> 6;
    int lane = threadIdx.x & 63;
    if (lane == 0) partial[wid] = s;
    __syncthreads();
    if (threadIdx.x == 0) {
        float deg = ((partial[0] + partial[1]) + (partial[2] + partial[3])) + 1.0f;
        ds[row] = rsqrtf(deg);
    }
}

// ---------------- Kernel 2: out[c][r] = bf16( in[r][c] * (scale ? scale[r] : 1) ) ----------------
__global__ __launch_bounds__(256) void k_transpose(const float* __restrict__ in,
                                                   ushort_t* __restrict__ out,
                                                   const float* __restrict__ scale,
                                                   int R, int C) {
    __shared__ float tile[64][65];
    int r0 = blockIdx.x * 64, c0 = blockIdx.y * 64;
    int t = threadIdx.x;
    int cl = t & 63;
    int rl0 = t >> 6;
#pragma unroll
    for (int i = 0; i < 16; ++i) {
        int r = rl0 + i * 4;
        float v = in[(size_t)(r0 + r) * C + c0 + cl];
        float sc = scale ? scale[r0 + r] : 1.0f;
        tile[r][cl] = v * sc;
    }
    __syncthreads();
#pragma unroll
    for (int i = 0; i < 16; ++i) {
        int c = rl0 + i * 4;
        int r = cl;
        out[(size_t)(c0 + c) * R + r0 + r] = f2bf(tile[r][c]);
    }
}

// ---------------- Kernel 3: mm1 = ds .* (adj @ y_t^T + ds .* x)  (bf16 out) ----------------
// adj fp32 [NN][NN]; yt bf16 [CC][NN] (col-major B); mm1 bf16 [NN][CC]
__global__ __launch_bounds__(256, 2) void k_gemm1(const float* __restrict__ adj,
                                                  const ushort_t* __restrict__ yt,
                                                  const float* __restrict__ ds,
                                                  const float* __restrict__ x,
                                                  ushort_t* __restrict__ mm1) {
    __shared__ __align__(16) ushort_t As[128 * 64];
    __shared__ __align__(16) ushort_t Bs[128 * 64];

    int t = threadIdx.x;
    int wid = t >> 6, lane = t & 63;
    int bid = blockIdx.x;
    bid = (bid & 7) * 32 + (bid >> 3);          // XCD swizzle (256 % 8 == 0, bijective)
    int cb = bid & 3, rb = bid >> 2;
    int rowBase = rb * 128, colBase = cb * 128;

    // A staging mapping: flat float4 f = i*256 + t -> row = f>>4, c4 = f&15
    int ar = t >> 4;
    int ac4 = t & 15;
    const float* aptr = adj + (size_t)(rowBase + ar) * NN + ac4 * 4;

    // B staging mapping
    int brow0 = t >> 3;
    int bs = t & 7;

    float4 areg[8];

    auto loadA = [&](int kt) {
        const float* p = aptr + kt * 64;
#pragma unroll
        for (int i = 0; i < 8; ++i)
            areg[i] = *(const float4*)(p + (size_t)i * 16 * NN);
    };
    auto writeA = [&]() {
#pragma unroll
        for (int i = 0; i < 8; ++i) {
            int row = i * 16 + ar;
            ushort4 u;
            u.x = f2bf(areg[i].x); u.y = f2bf(areg[i].y);
            u.z = f2bf(areg[i].z); u.w = f2bf(areg[i].w);
            *(ushort4*)((char*)As + row * 128 + ((ac4 * 8) ^ ((row & 7) << 4))) = u;
        }
    };
    auto stageB = [&](int kt) {
#pragma unroll
        for (int j = 0; j < 4; ++j) {
            int row = j * 32 + brow0;
            const char* g = (const char*)(yt + (size_t)(colBase + row) * NN + kt * 64 +
                                          ((bs ^ (row & 7)) << 3));
            char* l = (char*)Bs + j * 4096 + wid * 1024;   // wave-uniform base; HW adds lane*16
            gload_lds16(g, l);
        }
    };

    f32x4 acc[4][4] = {};
    int wr = wid >> 1, wc = wid & 1;
    int fr = lane & 15, fq = lane >> 4;

    loadA(0);
    for (int kt = 0; kt < NN / 64; ++kt) {
        writeA();
        stageB(kt);
        __syncthreads();
        if (kt + 1 < NN / 64) loadA(kt + 1);   // prefetch next A tile; overlaps MFMA below
#pragma unroll
        for (int ks = 0; ks < 2; ++ks) {
            short8 af[4], bf[4];
#pragma unroll
            for (int m = 0; m < 4; ++m) {
                int row = wr * 64 + m * 16 + fr;
                af[m] = *(const short8*)((const char*)As + row * 128 +
                                         ((ks * 64 + fq * 16) ^ ((row & 7) << 4)));
            }
#pragma unroll
            for (int n = 0; n < 4; ++n) {
                int col = wc * 64 + n * 16 + fr;
                bf[n] = *(const short8*)((const char*)Bs + col * 128 +
                                         ((ks * 64 + fq * 16) ^ ((col & 7) << 4)));
            }
#pragma unroll
            for (int m = 0; m < 4; ++m)
#pragma unroll
                for (int n = 0; n < 4; ++n)
                    acc[m][n] = __builtin_amdgcn_mfma_f32_16x16x32_bf16(af[m], bf[n], acc[m][n], 0, 0, 0);
        }
        __syncthreads();
    }

    // Epilogue: mm1 = ds[i]*(P + ds[i]*x[i][c]) -> bf16
#pragma unroll
    for (int m = 0; m < 4; ++m) {
#pragma unroll
        for (int j = 0; j < 4; ++j) {
            int gr = rowBase + wr * 64 + m * 16 + fq * 4 + j;
            float dsr = ds[gr];
#pragma unroll
            for (int n = 0; n < 4; ++n) {
                int gc = colBase + wc * 64 + n * 16 + fr;
                float p = acc[m][n][j];
                float v = dsr * (p + dsr * x[(size_t)gr * CC + gc]);
                mm1[(size_t)gr * CC + gc] = f2bf(v);
            }
        }
    }
}

// ---------------- Kernel 4: out = elu(mm1 @ w)  (f32 out) ----------------
// mm1 bf16 [NN][CC]; wt bf16 [CC][CC] (col-major B = w^T)
__global__ __launch_bounds__(256, 2) void k_gemm2(const ushort_t* __restrict__ mm1,
                                                  const ushort_t* __restrict__ wt,
                                                  float* __restrict__ out) {
    __shared__ __align__(16) ushort_t As[128 * 64];
    __shared__ __align__(16) ushort_t Bs[128 * 64];

    int t = threadIdx.x;
    int wid = t >> 6, lane = t & 63;
    int bid = blockIdx.x;
    bid = (bid & 7) * 32 + (bid >> 3);
    int cb = bid & 3, rb = bid >> 2;
    int rowBase = rb * 128, colBase = cb * 128;

    int srow0 = t >> 3, ss = t & 7;

    f32x4 acc[4][4] = {};
    int wr = wid >> 1, wc = wid & 1;
    int fr = lane & 15, fq = lane >> 4;

    for (int kt = 0; kt < CC / 64; ++kt) {
#pragma unroll
        for (int j = 0; j < 4; ++j) {
            int row = j * 32 + srow0;
            gload_lds16((const char*)(mm1 + (size_t)(rowBase + row) * CC + kt * 64 +
                                      ((ss ^ (row & 7)) << 3)),
                        (char*)As + j * 4096 + wid * 1024);
            gload_lds16((const char*)(wt + (size_t)(colBase + row) * CC + kt * 64 +
                                      ((ss ^ (row & 7)) << 3)),
                        (char*)Bs + j * 4096 + wid * 1024);
        }
        __syncthreads();
#pragma unroll
        for (int ks = 0; ks < 2; ++ks) {
            short8 af[4], bf[4];
#pragma unroll
            for (int m = 0; m < 4; ++m) {
                int row = wr * 64 + m * 16 + fr;
                af[m] = *(const short8*)((const char*)As + row * 128 +
                                         ((ks * 64 + fq * 16) ^ ((row & 7) << 4)));
            }
#pragma unroll
            for (int n = 0; n < 4; ++n) {
                int col = wc * 64 + n * 16 + fr;
                bf[n] = *(const short8*)((const char*)Bs + col * 128 +
                                         ((ks * 64 + fq * 16) ^ ((col & 7) << 4)));
            }
#pragma unroll
            for (int m = 0; m < 4; ++m)
#pragma unroll
                for (int n = 0; n < 4; ++n)
                    acc[m][n] = __builtin_amdgcn_mfma_f32_16x16x32_bf16(af[m], bf[n], acc[m][n], 0, 0, 0);
        }
        __syncthreads();
    }

    // Epilogue: ELU, store f32
#pragma unroll
    for (int m = 0; m < 4; ++m) {
#pragma unroll
        for (int j = 0; j < 4; ++j) {
            int gr = rowBase + wr * 64 + m * 16 + fq * 4 + j;
#pragma unroll
            for (int n = 0; n < 4; ++n) {
                int gc = colBase + wc * 64 + n * 16 + fr;
                float v = acc[m][n][j];
                out[(size_t)gr * CC + gc] = v > 0.f ? v : expm1f(v);
            }
        }
    }
}

extern "C" void kernel_launch(void* const* d_in, const int* in_sizes, int n_in,
                              void* d_out, int out_size, void* d_ws, size_t ws_size,
                              hipStream_t stream) {
    const float* x   = (const float*)d_in[0];   // [8192][512]
    const float* adj = (const float*)d_in[1];   // [8192][8192]
    const float* w   = (const float*)d_in[2];   // [512][512]
    float* out = (float*)d_out;                 // [8192][512]

    char* ws = (char*)d_ws;
    float*    ds  = (float*)ws;                                   // 32 KB
    ushort_t* yt  = (ushort_t*)(ws + (32u << 10));                // 8 MB   [512][8192]
    ushort_t* wt  = (ushort_t*)(ws + (32u << 10) + (8u << 20));   // 512 KB [512][512]
    ushort_t* mm1 = (ushort_t*)(ws + (32u << 10) + (8u << 20) + (512u << 10)); // 8 MB [8192][512]

    k_rowsum<<<NN, 256, 0, stream>>>(adj, ds);
    k_transpose<<<dim3(NN / 64, CC / 64), 256, 0, stream>>>(x, yt, ds, NN, CC);
    k_transpose<<<dim3(CC / 64, CC / 64), 256, 0, stream>>>(w, wt, nullptr, CC, CC);
    k_gemm1<<<256, 256, 0, stream>>>(adj, yt, ds, x, mm1);
    k_gemm2<<<256, 256, 0, stream>>>(mm1, wt, out);
}

// Round 2
// 220.521 us; speedup vs baseline: 1.2750x; 1.2750x over previous
//
#include <hip/hip_runtime.h>

#define NN 8192
#define CC 512

typedef __attribute__((ext_vector_type(8))) short short8;
typedef __attribute__((ext_vector_type(4))) float f32x4;
typedef unsigned short ushort_t;

__device__ __forceinline__ unsigned short f2bf(float f) {
    unsigned int u = __float_as_uint(f);
    u += 0x7FFF + ((u >> 16) & 1);
    return (unsigned short)(u >> 16);
}

__device__ __forceinline__ void gload_lds16(const void* g, void* l) {
    __builtin_amdgcn_global_load_lds((const __attribute__((address_space(1))) unsigned int*)g,
                                     (__attribute__((address_space(3))) unsigned int*)l,
                                     16, 0, 0);
}

// ---------------- Kernel 1: deg = rowsum(adj) + 1;  ds = rsqrt(deg) ----------------
__global__ __launch_bounds__(256) void k_rowsum(const float* __restrict__ adj,
                                                float* __restrict__ ds) {
    int row = blockIdx.x;
    const float4* p = (const float4*)(adj + (size_t)row * NN);
    float s = 0.f;
#pragma unroll
    for (int i = 0; i < 8; ++i) {
        float4 v = p[threadIdx.x + i * 256];
        s += (v.x + v.y) + (v.z + v.w);
    }
#pragma unroll
    for (int off = 32; off > 0; off >>= 1) s += __shfl_down(s, off, 64);
    __shared__ float partial[4];
    int wid = threadIdx.x >> 6;
    int lane = threadIdx.x & 63;
    if (lane == 0) partial[wid] = s;
    __syncthreads();
    if (threadIdx.x == 0) {
        float deg = ((partial[0] + partial[1]) + (partial[2] + partial[3])) + 1.0f;
        ds[row] = rsqrtf(deg);
    }
}

// ---------------- Kernel 2: out[c][r] = bf16( in[r][c] * (scale ? scale[r] : 1) ) ----------------
__global__ __launch_bounds__(256) void k_transpose(const float* __restrict__ in,
                                                   ushort_t* __restrict__ out,
                                                   const float* __restrict__ scale,
                                                   int R, int C) {
    __shared__ float tile[64][65];
    int r0 = blockIdx.x * 64, c0 = blockIdx.y * 64;
    int t = threadIdx.x;
    int cl = t & 63;
    int rl0 = t >> 6;
#pragma unroll
    for (int i = 0; i < 16; ++i) {
        int r = rl0 + i * 4;
        float v = in[(size_t)(r0 + r) * C + c0 + cl];
        float sc = scale ? scale[r0 + r] : 1.0f;
        tile[r][cl] = v * sc;
    }
    __syncthreads();
#pragma unroll
    for (int i = 0; i < 16; ++i) {
        int c = rl0 + i * 4;
        int r = cl;
        out[(size_t)(c0 + c) * R + r0 + r] = f2bf(tile[r][c]);
    }
}

// ---------------- Kernel 3: GEMM1  P = adj @ y  (y = ds .* x, col-major bf16) ----------------
// MODE 0: full-K, grid 256, epilogue mm1 = ds*(P + ds*x) -> bf16   (fallback, small ws)
// MODE 1: K/4 split, grid 1024, store f32 partial to part[ks]      (deterministic)
// MODE 2: K/4 split, grid 1024, atomicAdd into part (pre-zeroed)
template <int MODE>
__global__ __launch_bounds__(256, 4) void k_gemm1(const float* __restrict__ adj,
                                                  const ushort_t* __restrict__ yt,
                                                  const float* __restrict__ ds,
                                                  const float* __restrict__ x,
                                                  ushort_t* __restrict__ mm1,
                                                  float* __restrict__ part) {
    __shared__ __align__(16) ushort_t As[128 * 64];
    __shared__ __align__(16) ushort_t Bs[128 * 64];

    int t = threadIdx.x;
    int wid = t >> 6, lane = t & 63;

    int rowBase, colBase, kt0, ktN, ks;
    if (MODE == 0) {
        int bid = blockIdx.x;
        bid = (bid & 7) * 32 + (bid >> 3);      // XCD swizzle, bijective (256%8==0)
        colBase = (bid & 3) * 128;
        rowBase = (bid >> 2) * 128;
        kt0 = 0; ktN = NN / 64; ks = 0;
    } else {
        // gid -> (xcd, slot); 4 consecutive slots on an XCD = 4 col-blocks of one (rb,ks)
        int gid = blockIdx.x;
        int xcd = gid & 7, slot = gid >> 3;
        int cb = slot & 3;
        int g = (slot >> 2) * 8 + xcd;          // [0,256) = (rb,ks)
        int rb = g & 63; ks = g >> 6;
        rowBase = rb * 128; colBase = cb * 128;
        kt0 = ks * (NN / 64 / 4); ktN = kt0 + NN / 64 / 4;
    }

    // A staging mapping: flat float4 f = i*256 + t -> row = f>>4, c4 = f&15
    int ar = t >> 4;
    int ac4 = t & 15;
    const float* aptr = adj + (size_t)(rowBase + ar) * NN + ac4 * 4;

    // B staging mapping
    int brow0 = t >> 3;
    int bs = t & 7;

    float4 areg[8];

    auto loadA = [&](int kt) {
        const float* p = aptr + kt * 64;
#pragma unroll
        for (int i = 0; i < 8; ++i)
            areg[i] = *(const float4*)(p + (size_t)i * 16 * NN);
    };
    auto writeA = [&]() {
#pragma unroll
        for (int i = 0; i < 8; ++i) {
            int row = i * 16 + ar;
            ushort4 u;
            u.x = f2bf(areg[i].x); u.y = f2bf(areg[i].y);
            u.z = f2bf(areg[i].z); u.w = f2bf(areg[i].w);
            *(ushort4*)((char*)As + row * 128 + ((ac4 * 8) ^ ((row & 7) << 4))) = u;
        }
    };
    auto stageB = [&](int kt) {
#pragma unroll
        for (int j = 0; j < 4; ++j) {
            int row = j * 32 + brow0;
            const char* g = (const char*)(yt + (size_t)(colBase + row) * NN + kt * 64 +
                                          ((bs ^ (row & 7)) << 3));
            char* l = (char*)Bs + j * 4096 + wid * 1024;   // wave-uniform base; HW adds lane*16
            gload_lds16(g, l);
        }
    };

    f32x4 acc[4][4] = {};
    int wr = wid >> 1, wc = wid & 1;
    int fr = lane & 15, fq = lane >> 4;

    loadA(kt0);
    for (int kt = kt0; kt < ktN; ++kt) {
        writeA();
        stageB(kt);
        __syncthreads();
        if (kt + 1 < ktN) loadA(kt + 1);       // prefetch next A tile; overlaps MFMA below
#pragma unroll
        for (int ks2 = 0; ks2 < 2; ++ks2) {
            short8 af[4], bf[4];
#pragma unroll
            for (int m = 0; m < 4; ++m) {
                int row = wr * 64 + m * 16 + fr;
                af[m] = *(const short8*)((const char*)As + row * 128 +
                                         ((ks2 * 64 + fq * 16) ^ ((row & 7) << 4)));
            }
#pragma unroll
            for (int n = 0; n < 4; ++n) {
                int col = wc * 64 + n * 16 + fr;
                bf[n] = *(const short8*)((const char*)Bs + col * 128 +
                                         ((ks2 * 64 + fq * 16) ^ ((col & 7) << 4)));
            }
#pragma unroll
            for (int m = 0; m < 4; ++m)
#pragma unroll
                for (int n = 0; n < 4; ++n)
                    acc[m][n] = __builtin_amdgcn_mfma_f32_16x16x32_bf16(af[m], bf[n], acc[m][n], 0, 0, 0);
        }
        __syncthreads();
    }

#pragma unroll
    for (int m = 0; m < 4; ++m) {
#pragma unroll
        for (int j = 0; j < 4; ++j) {
            int gr = rowBase + wr * 64 + m * 16 + fq * 4 + j;
            float dsr = (MODE == 0) ? ds[gr] : 0.f;
#pragma unroll
            for (int n = 0; n < 4; ++n) {
                int gc = colBase + wc * 64 + n * 16 + fr;
                float p = acc[m][n][j];
                if (MODE == 0) {
                    float v = dsr * (p + dsr * x[(size_t)gr * CC + gc]);
                    mm1[(size_t)gr * CC + gc] = f2bf(v);
                } else if (MODE == 1) {
                    part[((size_t)ks * NN + gr) * CC + gc] = p;
                } else {
                    atomicAdd(&part[(size_t)gr * CC + gc], p);
                }
            }
        }
    }
}

// ---------------- Kernel 3b: mm1 = bf16( ds*(sum partials + ds*x) ) ----------------
__global__ __launch_bounds__(256) void k_finish(const float* __restrict__ part,
                                                const float* __restrict__ ds,
                                                const float* __restrict__ x,
                                                ushort_t* __restrict__ mm1,
                                                int nsplit) {
    size_t i = (size_t)blockIdx.x * 256 + threadIdx.x;   // f32x4 index, total NN*CC/4
    const f32x4* p = (const f32x4*)part;
    const size_t stride = (size_t)NN * CC / 4;
    f32x4 s = p[i];
    for (int k = 1; k < nsplit; ++k) s += p[i + (size_t)k * stride];
    int row = (int)(i >> 7);                             // (i*4) / 512
    float d = ds[row];
    f32x4 xv = ((const f32x4*)x)[i];
    ushort4 u;
    u.x = f2bf(d * (s[0] + d * xv[0]));
    u.y = f2bf(d * (s[1] + d * xv[1]));
    u.z = f2bf(d * (s[2] + d * xv[2]));
    u.w = f2bf(d * (s[3] + d * xv[3]));
    ((ushort4*)mm1)[i] = u;
}

// ---------------- Kernel 4: out = elu(mm1 @ w)  (f32 out) ----------------
__global__ __launch_bounds__(256, 2) void k_gemm2(const ushort_t* __restrict__ mm1,
                                                  const ushort_t* __restrict__ wt,
                                                  float* __restrict__ out) {
    __shared__ __align__(16) ushort_t As[128 * 64];
    __shared__ __align__(16) ushort_t Bs[128 * 64];

    int t = threadIdx.x;
    int wid = t >> 6, lane = t & 63;
    int bid = blockIdx.x;
    bid = (bid & 7) * 32 + (bid >> 3);
    int cb = bid & 3, rb = bid >> 2;
    int rowBase = rb * 128, colBase = cb * 128;

    int srow0 = t >> 3, ss = t & 7;

    f32x4 acc[4][4] = {};
    int wr = wid >> 1, wc = wid & 1;
    int fr = lane & 15, fq = lane >> 4;

    for (int kt = 0; kt < CC / 64; ++kt) {
#pragma unroll
        for (int j = 0; j < 4; ++j) {
            int row = j * 32 + srow0;
            gload_lds16((const char*)(mm1 + (size_t)(rowBase + row) * CC + kt * 64 +
                                      ((ss ^ (row & 7)) << 3)),
                        (char*)As + j * 4096 + wid * 1024);
            gload_lds16((const char*)(wt + (size_t)(colBase + row) * CC + kt * 64 +
                                      ((ss ^ (row & 7)) << 3)),
                        (char*)Bs + j * 4096 + wid * 1024);
        }
        __syncthreads();
#pragma unroll
        for (int ks = 0; ks < 2; ++ks) {
            short8 af[4], bf[4];
#pragma unroll
            for (int m = 0; m < 4; ++m) {
                int row = wr * 64 + m * 16 + fr;
                af[m] = *(const short8*)((const char*)As + row * 128 +
                                         ((ks * 64 + fq * 16) ^ ((row & 7) << 4)));
            }
#pragma unroll
            for (int n = 0; n < 4; ++n) {
                int col = wc * 64 + n * 16 + fr;
                bf[n] = *(const short8*)((const char*)Bs + col * 128 +
                                         ((ks * 64 + fq * 16) ^ ((col & 7) << 4)));
            }
#pragma unroll
            for (int m = 0; m < 4; ++m)
#pragma unroll
                for (int n = 0; n < 4; ++n)
                    acc[m][n] = __builtin_amdgcn_mfma_f32_16x16x32_bf16(af[m], bf[n], acc[m][n], 0, 0, 0);
        }
        __syncthreads();
    }

#pragma unroll
    for (int m = 0; m < 4; ++m) {
#pragma unroll
        for (int j = 0; j < 4; ++j) {
            int gr = rowBase + wr * 64 + m * 16 + fq * 4 + j;
#pragma unroll
            for (int n = 0; n < 4; ++n) {
                int gc = colBase + wc * 64 + n * 16 + fr;
                float v = acc[m][n][j];
                out[(size_t)gr * CC + gc] = v > 0.f ? v : expm1f(v);
            }
        }
    }
}

extern "C" void kernel_launch(void* const* d_in, const int* in_sizes, int n_in,
                              void* d_out, int out_size, void* d_ws, size_t ws_size,
                              hipStream_t stream) {
    const float* x   = (const float*)d_in[0];   // [8192][512]
    const float* adj = (const float*)d_in[1];   // [8192][8192]
    const float* w   = (const float*)d_in[2];   // [512][512]
    float* out = (float*)d_out;                 // [8192][512]

    char* ws = (char*)d_ws;
    size_t off = 0;
    float*    ds  = (float*)(ws + off);  off += 32u << 10;              // 32 KB
    ushort_t* yt  = (ushort_t*)(ws + off);  off += 8u << 20;            // 8 MB [512][8192]
    ushort_t* wt  = (ushort_t*)(ws + off);  off += 512u << 10;          // 512 KB
    ushort_t* mm1 = (ushort_t*)(ws + off);  off += 8u << 20;            // 8 MB [8192][512]
    float*    part = (float*)(ws + off);                                 // partials
    const size_t oneBuf = (size_t)NN * CC * 4;                           // 16 MB

    k_rowsum<<<NN, 256, 0, stream>>>(adj, ds);
    k_transpose<<<dim3(NN / 64, CC / 64), 256, 0, stream>>>(x, yt, ds, NN, CC);
    k_transpose<<<dim3(CC / 64, CC / 64), 256, 0, stream>>>(w, wt, nullptr, CC, CC);

    if (ws_size >= off + 4 * oneBuf) {
        // deterministic split-K=4 with separate partial buffers
        k_gemm1<1><<<1024, 256, 0, stream>>>(adj, yt, ds, x, mm1, part);
        k_finish<<<NN * CC / 4 / 256, 256, 0, stream>>>(part, ds, x, mm1, 4);
    } else if (ws_size >= off + oneBuf) {
        hipMemsetAsync(part, 0, oneBuf, stream);
        k_gemm1<2><<<1024, 256, 0, stream>>>(adj, yt, ds, x, mm1, part);
        k_finish<<<NN * CC / 4 / 256, 256, 0, stream>>>(part, ds, x, mm1, 1);
    } else {
        k_gemm1<0><<<256, 256, 0, stream>>>(adj, yt, ds, x, mm1, part);
    }

    k_gemm2<<<256, 256, 0, stream>>>(mm1, wt, out);
}